// Round 10
// baseline (632.489 us; speedup 1.0000x reference)
//
#include <hip/hip_runtime.h>
#include <cstdint>

// ---------------------------------------------------------------------------
// DirGraphSAGE round 10:
//  - k_agg7: quarter-major slabs (r6: FETCH 97MB proven) + 4 lanes/node
//    private accumulators (r8: VALU 21% proven) + IN-KERNEL quarter loop:
//    whole 1564-block grid co-resident -> all waves sweep slab q together
//    (3.2MB < 4MB per-XCD L2). lst(4B)+L2-resident inv instead of 8B payload.
//    __syncthreads between quarters to limit drift. No early returns.
//  - k_conv / k_gemm: r7's quarter-major indexing (validated).
//  - CSR build (padded-counter atomics, rank trick), scan, split-W MFMA GEMM,
//    bf16 relu chaining unchanged.
// ---------------------------------------------------------------------------

typedef __bf16 bf16x8 __attribute__((ext_vector_type(8)));
typedef float f32x4 __attribute__((ext_vector_type(4)));

__device__ __forceinline__ unsigned short f2bf(float f) {
  unsigned u = __float_as_uint(f);
  u += 0x7FFFu + ((u >> 16) & 1u);   // round-to-nearest-even
  return (unsigned short)(u >> 16);
}
__device__ __forceinline__ float bflo(unsigned u) { return __uint_as_float(u << 16); }
__device__ __forceinline__ float bfhi(unsigned u) { return __uint_as_float(u & 0xFFFF0000u); }

// Padded counters: one 4B counter per 64B line (stride 16 ints).
__global__ __launch_bounds__(256) void k_degrees(const int* __restrict__ src,
                                                 const int* __restrict__ dst,
                                                 int* __restrict__ cin_p,
                                                 int* __restrict__ cout_p,
                                                 int* __restrict__ rankf,
                                                 int* __restrict__ rankb, int E) {
  int e = blockIdx.x * 256 + threadIdx.x;
  if (e >= E) return;
  int s = src[e], d = dst[e];
  rankf[e] = atomicAdd(&cin_p[(size_t)d * 16], 1);   // rank in fwd list (by dst)
  rankb[e] = atomicAdd(&cout_p[(size_t)s * 16], 1);  // rank in bwd list (by src)
}

// Reads padded counters; writes inv factors AND dense counts for the scan.
__global__ __launch_bounds__(256) void k_inv(const int* __restrict__ cin_p,
                                             const int* __restrict__ cout_p,
                                             float* __restrict__ inv_in,
                                             float* __restrict__ inv_out,
                                             int* __restrict__ cin_d,
                                             int* __restrict__ cout_d, int n) {
  int i = blockIdx.x * 256 + threadIdx.x;
  if (i >= n) return;
  int ci = cin_p[(size_t)i * 16], co = cout_p[(size_t)i * 16];
  inv_in[i]  = 1.0f / (float)max(ci, 1);
  inv_out[i] = 1.0f / (float)max(co, 1);
  cin_d[i] = ci;
  cout_d[i] = co;
}

// --- 3-phase multi-block exclusive scan (CHUNK=2048/block, y-dim = which array)
__global__ __launch_bounds__(256) void k_scan_part(const int* __restrict__ cntA,
                                                   const int* __restrict__ cntB,
                                                   int* __restrict__ partA,
                                                   int* __restrict__ partB, int n) {
  const int* cnt = blockIdx.y ? cntB : cntA;
  int* part = blockIdx.y ? partB : partA;
  __shared__ int red[256];
  int t = threadIdx.x;
  int base = blockIdx.x * 2048 + t * 8;
  int s = 0;
#pragma unroll
  for (int i = 0; i < 8; ++i) {
    int idx = base + i;
    if (idx < n) s += cnt[idx];
  }
  red[t] = s;
  __syncthreads();
  for (int o = 128; o > 0; o >>= 1) {
    if (t < o) red[t] += red[t + o];
    __syncthreads();
  }
  if (t == 0) part[blockIdx.x] = red[0];
}

__global__ __launch_bounds__(64) void k_scan_tops(int* __restrict__ partA,
                                                  int* __restrict__ partB, int nb) {
  int* part = blockIdx.y ? partB : partA;
  if (threadIdx.x == 0) {
    int run = 0;
    for (int i = 0; i < nb; ++i) { int v = part[i]; part[i] = run; run += v; }
  }
}

__global__ __launch_bounds__(256) void k_scan_out(const int* __restrict__ cntA,
                                                  const int* __restrict__ cntB,
                                                  const int* __restrict__ partA,
                                                  const int* __restrict__ partB,
                                                  int* __restrict__ offA,
                                                  int* __restrict__ offB, int n) {
  const int* cnt = blockIdx.y ? cntB : cntA;
  const int* part = blockIdx.y ? partB : partA;
  int* off = blockIdx.y ? offB : offA;
  __shared__ int ts[256];
  int t = threadIdx.x;
  int base = blockIdx.x * 2048 + t * 8;
  int v[8];
  int s = 0;
#pragma unroll
  for (int i = 0; i < 8; ++i) {
    int idx = base + i;
    int c = (idx < n) ? cnt[idx] : 0;
    v[i] = s;          // exclusive prefix within thread
    s += c;
  }
  ts[t] = s;
  __syncthreads();
  for (int o = 1; o < 256; o <<= 1) {
    int val = (t >= o) ? ts[t - o] : 0;
    __syncthreads();
    ts[t] += val;
    __syncthreads();
  }
  int blockbase = part[blockIdx.x] + (t ? ts[t - 1] : 0);
#pragma unroll
  for (int i = 0; i < 8; ++i) {
    int idx = base + i;
    if (idx <= n) off[idx] = blockbase + v[i];   // idx==n writes the total
  }
}

// Atomic-free fill using precomputed ranks (plain index lists).
__global__ __launch_bounds__(256) void k_fill(const int* __restrict__ src,
                                              const int* __restrict__ dst,
                                              const int* __restrict__ offf,
                                              const int* __restrict__ offb,
                                              const int* __restrict__ rankf,
                                              const int* __restrict__ rankb,
                                              int* __restrict__ lstf,
                                              int* __restrict__ lstb, int E) {
  int e = blockIdx.x * 256 + threadIdx.x;
  if (e >= E) return;
  int s = src[e], d = dst[e];
  lstf[offf[d] + rankf[e]] = s;   // fwd: grouped by dst, holds src
  lstb[offb[s] + rankb[e]] = d;   // bwd: grouped by src, holds dst
}

// x (fp32, N x 128) -> xbu quarter-major: uint2 layout [4][n][8]
__global__ __launch_bounds__(256) void k_conv(const float* __restrict__ x,
                                              unsigned* __restrict__ xbu, int n) {
  int idx = blockIdx.x * 256 + threadIdx.x;  // over n*32 float4s
  if (idx >= n * 32) return;
  int v = idx >> 5, w2 = idx & 31;           // w2: uint2 within row (32 per row)
  int q = w2 >> 3, c2 = w2 & 7;              // quarter, uint2 within quarter
  float4 xv = ((const float4*)x)[idx];
  unsigned u0 = (unsigned)f2bf(xv.x) | ((unsigned)f2bf(xv.y) << 16);
  unsigned u1 = (unsigned)f2bf(xv.z) | ((unsigned)f2bf(xv.w) << 16);
  ((uint2*)xbu)[(size_t)q * n * 8 + (size_t)v * 8 + c2] = make_uint2(u0, u1);
}

// W (fp32 384x128) -> Wt_hi, Wt_lo (bf16, 128x384, transposed, packed x2)
__global__ __launch_bounds__(256) void k_wconv3(
    const float* __restrict__ Wa, const float* __restrict__ Wb,
    const float* __restrict__ Wc,
    unsigned* __restrict__ Ha, unsigned* __restrict__ Hb, unsigned* __restrict__ Hc,
    unsigned* __restrict__ La, unsigned* __restrict__ Lb, unsigned* __restrict__ Lc) {
  const float* W = (blockIdx.y == 0) ? Wa : ((blockIdx.y == 1) ? Wb : Wc);
  unsigned* Wth = (blockIdx.y == 0) ? Ha : ((blockIdx.y == 1) ? Hb : Hc);
  unsigned* Wtl = (blockIdx.y == 0) ? La : ((blockIdx.y == 1) ? Lb : Lc);
  int t = blockIdx.x * 256 + threadIdx.x;   // 128*192 threads; t = j*192 + k2
  if (t >= 128 * 192) return;
  int j = t / 192, k2 = t - j * 192;
  int k = k2 * 2;
  float w0 = W[k * 128 + j], w1 = W[(k + 1) * 128 + j];
  unsigned short h0 = f2bf(w0), h1 = f2bf(w1);
  float l0 = w0 - __uint_as_float((unsigned)h0 << 16);
  float l1 = w1 - __uint_as_float((unsigned)h1 << 16);
  Wth[t] = (unsigned)h0 | ((unsigned)h1 << 16);
  Wtl[t] = (unsigned)f2bf(l0) | ((unsigned)f2bf(l1) << 16);
}

// Quarter-major agg with IN-KERNEL quarter loop.
// 4 lanes/node (uint4 col c of the 64B quarter row), 16 nodes/wave,
// 64 nodes/block. grid: x = ceil(N/64), y = dir. All blocks co-resident ->
// every wave works on the same 3.2MB slab (fits 4MB per-XCD L2).
__global__ __launch_bounds__(256) void k_agg7(const uint4* __restrict__ xb,
                                              const int* __restrict__ offA,
                                              const int* __restrict__ lstA,
                                              const float* __restrict__ invA,
                                              const int* __restrict__ offB,
                                              const int* __restrict__ lstB,
                                              const float* __restrict__ invB,
                                              uint4* __restrict__ outA,
                                              uint4* __restrict__ outB, int n) {
  int lane = threadIdx.x & 63;
  int gi = lane >> 2, c = lane & 3;   // node group (16/wave), uint4 col in quarter
  int node = ((blockIdx.x * 256 + threadIdx.x) >> 6) * 16 + gi;
  bool active = node < n;
  const int* off = blockIdx.y ? offB : offA;
  const int* lst = blockIdx.y ? lstB : lstA;
  const float* inv = blockIdx.y ? invB : invA;
  uint4* out = blockIdx.y ? outB : outA;
  int beg = active ? off[node] : 0;
  int end = active ? off[node + 1] : 0;
  size_t n4 = (size_t)n * 4;

  for (int q = 0; q < 4; ++q) {
    const uint4* slab = xb + (size_t)q * n4;
    float acc[8];
#pragma unroll
    for (int k = 0; k < 8; ++k) acc[k] = 0.f;
    int i = beg;
    for (; i + 1 < end; i += 2) {
      int u0 = lst[i], u1 = lst[i + 1];
      float w0 = inv[u0], w1 = inv[u1];
      uint4 r0 = slab[(size_t)u0 * 4 + c];
      uint4 r1 = slab[(size_t)u1 * 4 + c];
      acc[0] = fmaf(bflo(r0.x), w0, acc[0]); acc[1] = fmaf(bfhi(r0.x), w0, acc[1]);
      acc[2] = fmaf(bflo(r0.y), w0, acc[2]); acc[3] = fmaf(bfhi(r0.y), w0, acc[3]);
      acc[4] = fmaf(bflo(r0.z), w0, acc[4]); acc[5] = fmaf(bfhi(r0.z), w0, acc[5]);
      acc[6] = fmaf(bflo(r0.w), w0, acc[6]); acc[7] = fmaf(bfhi(r0.w), w0, acc[7]);
      acc[0] = fmaf(bflo(r1.x), w1, acc[0]); acc[1] = fmaf(bfhi(r1.x), w1, acc[1]);
      acc[2] = fmaf(bflo(r1.y), w1, acc[2]); acc[3] = fmaf(bfhi(r1.y), w1, acc[3]);
      acc[4] = fmaf(bflo(r1.z), w1, acc[4]); acc[5] = fmaf(bfhi(r1.z), w1, acc[5]);
      acc[6] = fmaf(bflo(r1.w), w1, acc[6]); acc[7] = fmaf(bfhi(r1.w), w1, acc[7]);
    }
    if (i < end) {
      int u0 = lst[i];
      float w0 = inv[u0];
      uint4 r0 = slab[(size_t)u0 * 4 + c];
      acc[0] = fmaf(bflo(r0.x), w0, acc[0]); acc[1] = fmaf(bfhi(r0.x), w0, acc[1]);
      acc[2] = fmaf(bflo(r0.y), w0, acc[2]); acc[3] = fmaf(bfhi(r0.y), w0, acc[3]);
      acc[4] = fmaf(bflo(r0.z), w0, acc[4]); acc[5] = fmaf(bfhi(r0.z), w0, acc[5]);
      acc[6] = fmaf(bflo(r0.w), w0, acc[6]); acc[7] = fmaf(bfhi(r0.w), w0, acc[7]);
    }
    if (active) {
      uint4 o;
      o.x = (unsigned)f2bf(acc[0]) | ((unsigned)f2bf(acc[1]) << 16);
      o.y = (unsigned)f2bf(acc[2]) | ((unsigned)f2bf(acc[3]) << 16);
      o.z = (unsigned)f2bf(acc[4]) | ((unsigned)f2bf(acc[5]) << 16);
      o.w = (unsigned)f2bf(acc[6]) | ((unsigned)f2bf(acc[7]) << 16);
      out[(size_t)q * n4 + (size_t)node * 4 + c] = o;
    }
    __syncthreads();   // keep the block's 4 waves on the same slab
  }
}

// MFMA GEMM: h = bias + [xbu|fwdb|bwdb][v,:] @ (W_hi + W_lo)
// A operands quarter-major [4][n][4 uint4]; chunk kc uses slab kc&3.
// If outb: write bf16(relu(h)) quarter-major (next layer's xbu). Else fp32 outf.
__global__ __launch_bounds__(256) void k_gemm(const unsigned* __restrict__ xbu,
                                              const unsigned* __restrict__ fwdb,
                                              const unsigned* __restrict__ bwdb,
                                              const unsigned* __restrict__ Wth,
                                              const unsigned* __restrict__ Wtl,
                                              const float* __restrict__ bias,
                                              unsigned short* __restrict__ outb,
                                              float* __restrict__ outf, int n) {
  __shared__ uint4 sA[512];    // 8 KB: A chunk, frag order [mt][q][m]
  __shared__ uint4 sWh[512];   // 8 KB
  __shared__ uint4 sWl[512];   // 8 KB
  int tid = threadIdx.x;
  int bm0 = blockIdx.x * 128;
  int w = tid >> 6, lane = tid & 63;
  size_t n4 = (size_t)n * 4;

  f32x4 acc[2][8];
#pragma unroll
  for (int mt = 0; mt < 2; ++mt)
#pragma unroll
    for (int nt = 0; nt < 8; ++nt) acc[mt][nt] = (f32x4){0.f, 0.f, 0.f, 0.f};

  const uint4* Wh4 = (const uint4*)Wth;   // row j: 48 uint4 (384 bf16)
  const uint4* Wl4 = (const uint4*)Wtl;

  for (int kc = 0; kc < 12; ++kc) {
    const uint4* src4 = (const uint4*)((kc < 4) ? xbu : ((kc < 8) ? fwdb : bwdb));
    size_t slab = (size_t)(kc & 3) * n4;
    __syncthreads();
#pragma unroll
    for (int p = 0; p < 2; ++p) {
      int f = tid + p * 256;          // 0..511
      int r = f >> 2, q = f & 3;      // r: row/col-of-W, q: uint4 in slab row
      int slot = (r >> 4) * 64 + q * 16 + (r & 15);
      int v = bm0 + r;
      uint4 val = make_uint4(0u, 0u, 0u, 0u);
      if (v < n) val = src4[slab + (size_t)v * 4 + q];
      sA[slot] = val;
      sWh[slot] = Wh4[(size_t)r * 48 + kc * 4 + q];
      sWl[slot] = Wl4[(size_t)r * 48 + kc * 4 + q];
    }
    __syncthreads();
    bf16x8 a0 = ((const bf16x8*)sA)[(2 * w) * 64 + lane];
    bf16x8 a1 = ((const bf16x8*)sA)[(2 * w + 1) * 64 + lane];
#pragma unroll
    for (int nt = 0; nt < 8; ++nt) {
      bf16x8 bh = ((const bf16x8*)sWh)[nt * 64 + lane];
      bf16x8 bl = ((const bf16x8*)sWl)[nt * 64 + lane];
      acc[0][nt] = __builtin_amdgcn_mfma_f32_16x16x32_bf16(a0, bh, acc[0][nt], 0, 0, 0);
      acc[0][nt] = __builtin_amdgcn_mfma_f32_16x16x32_bf16(a0, bl, acc[0][nt], 0, 0, 0);
      acc[1][nt] = __builtin_amdgcn_mfma_f32_16x16x32_bf16(a1, bh, acc[1][nt], 0, 0, 0);
      acc[1][nt] = __builtin_amdgcn_mfma_f32_16x16x32_bf16(a1, bl, acc[1][nt], 0, 0, 0);
    }
  }

  // Epilogue. C layout: col = lane&15, row = (lane>>4)*4 + reg  (m89-verified)
  int col = lane & 15;
  float bv[8];
#pragma unroll
  for (int nt = 0; nt < 8; ++nt) bv[nt] = bias[nt * 16 + col];
#pragma unroll
  for (int mt = 0; mt < 2; ++mt) {
    int rowbase = bm0 + w * 32 + mt * 16 + (lane >> 4) * 4;
#pragma unroll
    for (int reg = 0; reg < 4; ++reg) {
      int row = rowbase + reg;
      if (row >= n) continue;
      if (outb) {
        // quarter-major bf16: element j = nt*16+col; quarter = nt>>1
#pragma unroll
        for (int nt = 0; nt < 8; ++nt) {
          float t = fmaxf(acc[mt][nt][reg] + bv[nt], 0.f);   // relu layers
          size_t addr = (size_t)(nt >> 1) * n * 32 + (size_t)row * 32 +
                        (nt & 1) * 16 + col;
          outb[addr] = f2bf(t);
        }
      } else {
#pragma unroll
        for (int nt = 0; nt < 8; ++nt) {
          float t = acc[mt][nt][reg] + bv[nt];
          outf[(size_t)row * 128 + nt * 16 + col] = t;
        }
      }
    }
  }
}

extern "C" void kernel_launch(void* const* d_in, const int* in_sizes, int n_in,
                              void* d_out, int out_size, void* d_ws, size_t ws_size,
                              hipStream_t stream) {
  const int D = 128;
  const int N = in_sizes[0] / D;
  const int E = in_sizes[7];

  const float* x  = (const float*)d_in[0];
  const float* W0 = (const float*)d_in[1];
  const float* b0 = (const float*)d_in[2];
  const float* W1 = (const float*)d_in[3];
  const float* b1 = (const float*)d_in[4];
  const float* W2 = (const float*)d_in[5];
  const float* b2 = (const float*)d_in[6];
  const int* src  = (const int*)d_in[7];
  const int* dst  = (const int*)d_in[8];
  float* out = (float*)d_out;

  char* p = (char*)d_ws;
  auto alloc = [&](size_t bytes) -> char* {
    char* r = p;
    p += (bytes + 15) & ~(size_t)15;
    return r;
  };
  float* invout = (float*)alloc((size_t)N * 4);
  float* invin  = (float*)alloc((size_t)N * 4);
  int* cin_p  = (int*)alloc((size_t)N * 64);   // padded: 1 counter / 64B line
  int* cout_p = (int*)alloc((size_t)N * 64);
  int* cin_d  = (int*)alloc((size_t)N * 4);    // dense for scan
  int* cout_d = (int*)alloc((size_t)N * 4);
  int* offf = (int*)alloc((size_t)(N + 1) * 4);
  int* offb = (int*)alloc((size_t)(N + 1) * 4);
  int* rankf = (int*)alloc((size_t)E * 4);
  int* rankb = (int*)alloc((size_t)E * 4);
  int* lstf = (int*)alloc((size_t)E * 4);
  int* lstb = (int*)alloc((size_t)E * 4);
  unsigned* xbu = (unsigned*)alloc((size_t)N * 64 * 4);   // quarter-major bf16x2
  unsigned* fwdb = (unsigned*)alloc((size_t)N * 64 * 4);
  unsigned* bwdb = (unsigned*)alloc((size_t)N * 64 * 4);
  unsigned* Wth[3], *Wtl[3];
  for (int l = 0; l < 3; ++l) {
    Wth[l] = (unsigned*)alloc((size_t)128 * 192 * 4);
    Wtl[l] = (unsigned*)alloc((size_t)128 * 192 * 4);
  }
  int nbScan = (N + 1 + 2047) / 2048;
  int* partA = (int*)alloc((size_t)(nbScan + 1) * 4);
  int* partB = (int*)alloc((size_t)(nbScan + 1) * 4);

  hipMemsetAsync(cin_p, 0, (size_t)2 * N * 64, stream);  // cin_p+cout_p contiguous

  k_degrees<<<(E + 255) / 256, 256, 0, stream>>>(src, dst, cin_p, cout_p, rankf,
                                                 rankb, E);
  k_inv<<<(N + 255) / 256, 256, 0, stream>>>(cin_p, cout_p, invin, invout,
                                             cin_d, cout_d, N);
  k_scan_part<<<dim3(nbScan, 2), 256, 0, stream>>>(cin_d, cout_d, partA, partB, N);
  k_scan_tops<<<dim3(1, 2), 64, 0, stream>>>(partA, partB, nbScan);
  k_scan_out<<<dim3(nbScan, 2), 256, 0, stream>>>(cin_d, cout_d, partA, partB,
                                                  offf, offb, N);
  k_fill<<<(E + 255) / 256, 256, 0, stream>>>(src, dst, offf, offb, rankf, rankb,
                                              lstf, lstb, E);
  k_wconv3<<<dim3((128 * 192 + 255) / 256, 3), 256, 0, stream>>>(
      W0, W1, W2, Wth[0], Wth[1], Wth[2], Wtl[0], Wtl[1], Wtl[2]);

  const float* bs[3] = {b0, b1, b2};
  int aggBlocks = (N + 63) / 64;          // 64 nodes/block (4 lanes/node); dir=y
  int convBlocks = (N * 32 + 255) / 256;
  int gemmBlocks = (N + 127) / 128;

  k_conv<<<convBlocks, 256, 0, stream>>>(x, xbu, N);   // layer-0 input only
  for (int l = 0; l < 3; ++l) {
    // fwd[v] = sum_{s:(s,v)} x[s]*inv_out[s]; bwd[v] = sum_{d:(v,d)} x[d]*inv_in[d]
    k_agg7<<<dim3(aggBlocks, 2), 256, 0, stream>>>(
        (const uint4*)xbu, offf, lstf, invout, offb, lstb, invin,
        (uint4*)fwdb, (uint4*)bwdb, N);
    if (l < 2) {
      k_gemm<<<gemmBlocks, 256, 0, stream>>>(xbu, fwdb, bwdb, Wth[l], Wtl[l],
                                             bs[l], (unsigned short*)xbu, nullptr, N);
    } else {
      k_gemm<<<gemmBlocks, 256, 0, stream>>>(xbu, fwdb, bwdb, Wth[l], Wtl[l],
                                             bs[l], nullptr, out, N);
    }
  }
}